// Round 20
// baseline (166.625 us; speedup 1.0000x reference)
//
#include <hip/hip_runtime.h>
#include <hip/hip_bf16.h>
#include <stdint.h>

#define CIN 128
#define COUT 256
#define NIN 400000
#define MOUT 100000
#define KOFFS 8
#define EPSV 1e-4f
#define BM 32
#define NBLK (MOUT / BM)              // 3125, exact (no tail anywhere)
#define THREADS 512
#define ZROW 128

typedef __attribute__((ext_vector_type(8))) short short8;
typedef __attribute__((ext_vector_type(4))) float f32x4;

__device__ __forceinline__ unsigned f2bf_u(float f) {
  union { float f; unsigned u; } v; v.f = f;
  return (v.u + 0x7FFFu + ((v.u >> 16) & 1u)) >> 16;  // RNE bf16
}

__device__ __forceinline__ unsigned pk2bf(float a, float b) {
  __hip_bfloat162 p = __float22bfloat162_rn(make_float2(a, b));
  union { __hip_bfloat162 h; unsigned u; } c; c.h = p;
  return c.u;                          // v_cvt_pk_bf16_f32, 1 instr
}

// ---------------------------------------------------------------------------
// Kernel 0: W[k][c][n] fp32 -> Wt in MFMA-fragment order (R14 layout).
// ---------------------------------------------------------------------------
__global__ void prep_kernel(const float* __restrict__ W,
                            unsigned short* __restrict__ Wt) {
  __shared__ unsigned short t[64][257];
  const int s = blockIdx.x;
  const int tid = threadIdx.x;  // 256
  const int koff = s >> 1;
  const int cbase = (s & 1) * 64;
  const float* Wk = W + koff * (CIN * COUT);
  #pragma unroll 8
  for (int c = 0; c < 64; ++c)
    t[c][tid] = (unsigned short)f2bf_u(Wk[(cbase + c) * COUT + tid]);
  __syncthreads();
  uint4* dst = (uint4*)((char*)Wt + s * 32768);
  #pragma unroll
  for (int p = 0; p < 8; ++p) {
    int f = p * 256 + tid;
    int wn = f >> 8, rem = f & 255;
    int g = rem >> 6, l = rem & 63;
    int ks = g >> 1, ni = g & 1;
    int n = wn * 32 + ni * 16 + (l & 15);
    int cb = ks * 32 + ((l >> 4) << 3);
    uint4 w;
    w.x = (unsigned)t[cb + 0][n] | ((unsigned)t[cb + 1][n] << 16);
    w.y = (unsigned)t[cb + 2][n] | ((unsigned)t[cb + 3][n] << 16);
    w.z = (unsigned)t[cb + 4][n] | ((unsigned)t[cb + 5][n] << 16);
    w.w = (unsigned)t[cb + 6][n] | ((unsigned)t[cb + 7][n] << 16);
    dst[f] = w;
  }
}

// ---------------------------------------------------------------------------
// Kernel 1: gather-GEMM conv — R18 structure at BM=32: LDS 34KB -> 4
// blocks/CU (2x occupancy), fragment-major B (the fix R11 lacked), exact
// tiling (no tail/bounds checks). acc[2][2] per wave (32r x 32c).
// ---------------------------------------------------------------------------
__global__ __launch_bounds__(THREADS, 4) void conv_kernel(
    const float* __restrict__ feats,
    const unsigned short* __restrict__ Wt,
    const int* __restrict__ gidx,
    unsigned short* __restrict__ rawout,
    float* __restrict__ out32,
    float* __restrict__ partial) {
  __shared__ unsigned short Asm[129 * 128];   // 129 rows x 256 B (row 128 = 0)
  __shared__ int IDXs[BM * KOFFS];            // 256 ints

  const int tid = threadIdx.x;
  const int lane = tid & 63;
  const int wave = tid >> 6;       // col-group 0..7 (32 cols each)
  const int row16 = lane & 15;
  const int quad = lane >> 4;
  const long base_m = (long)blockIdx.x * BM;
  const long in_base = 4 * base_m;            // 3125*128 = 400000 exact

  // ---- B frags for step 0: issue FIRST (L2 latency under staging) ----
  short8 B0a, B0b, B1a, B1b;
  auto B_LOAD0 = [&](int s) {
    const char* bp = (const char*)Wt + s * 32768 + (wave << 12) + (lane << 4);
    B0a = *(const short8*)(bp);
    B0b = *(const short8*)(bp + 1024);
  };
  auto B_LOAD1 = [&](int s) {
    const char* bp = (const char*)Wt + s * 32768 + (wave << 12) + 2048 + (lane << 4);
    B1a = *(const short8*)(bp);
    B1b = *(const short8*)(bp + 1024);
  };
  B_LOAD0(0);

  if (tid < BM * KOFFS) {
    int idx = gidx[base_m * KOFFS + tid];
    long li = (long)idx - in_base;
    IDXs[tid] = ((unsigned long)li > 127ul) ? ZROW : (int)li;
  }
  if (tid < 16) *(uint4*)((char*)Asm + ZROW * 256 + tid * 16) = make_uint4(0, 0, 0, 0);

  // ---- linear A stage: 128 rows x 256B bf16, 8 float4/thread, cvt_pk ----
  {
    const float4* f4 = (const float4*)feats + in_base * 32;
    float4 v[8];
    #pragma unroll
    for (int p = 0; p < 8; ++p) v[p] = f4[p * THREADS + tid];
    #pragma unroll
    for (int p = 0; p < 8; ++p) {
      int j = p * THREADS + tid;
      int row = j >> 5, ch4 = j & 31;
      uint2 w;
      w.x = pk2bf(v[p].x, v[p].y);
      w.y = pk2bf(v[p].z, v[p].w);
      *(uint2*)((char*)Asm + row * 256 + ((ch4 * 8) ^ ((row & 15) << 4))) = w;
    }
  }
  __syncthreads();

  f32x4 acc[2][2];
  #pragma unroll
  for (int mi = 0; mi < 2; ++mi)
    #pragma unroll
    for (int ni = 0; ni < 2; ++ni)
      acc[mi][ni] = (f32x4){0.f, 0.f, 0.f, 0.f};

  int li0, li1;
  auto LI_LOAD = [&](int k) {
    li0 = IDXs[(row16) * 8 + k];
    li1 = IDXs[(row16 + 16) * 8 + k];
  };
  auto AF = [&](int li, int inner) -> short8 {
    return *(const short8*)((const char*)Asm + li * 256 +
                            (inner ^ ((li & 15) << 4)));
  };

  auto MMA0 = [&](int half) {
    const int inner = (half << 7) + (quad << 4);
    short8 a0 = AF(li0, inner), a1 = AF(li1, inner);
    __builtin_amdgcn_s_setprio(1);
    acc[0][0] = __builtin_amdgcn_mfma_f32_16x16x32_bf16(a0, B0a, acc[0][0], 0, 0, 0);
    acc[0][1] = __builtin_amdgcn_mfma_f32_16x16x32_bf16(a0, B0b, acc[0][1], 0, 0, 0);
    acc[1][0] = __builtin_amdgcn_mfma_f32_16x16x32_bf16(a1, B0a, acc[1][0], 0, 0, 0);
    acc[1][1] = __builtin_amdgcn_mfma_f32_16x16x32_bf16(a1, B0b, acc[1][1], 0, 0, 0);
    __builtin_amdgcn_s_setprio(0);
  };
  auto MMA1 = [&](int half) {
    const int inner = (half << 7) + 64 + (quad << 4);
    short8 a0 = AF(li0, inner), a1 = AF(li1, inner);
    __builtin_amdgcn_s_setprio(1);
    acc[0][0] = __builtin_amdgcn_mfma_f32_16x16x32_bf16(a0, B1a, acc[0][0], 0, 0, 0);
    acc[0][1] = __builtin_amdgcn_mfma_f32_16x16x32_bf16(a0, B1b, acc[0][1], 0, 0, 0);
    acc[1][0] = __builtin_amdgcn_mfma_f32_16x16x32_bf16(a1, B1a, acc[1][0], 0, 0, 0);
    acc[1][1] = __builtin_amdgcn_mfma_f32_16x16x32_bf16(a1, B1b, acc[1][1], 0, 0, 0);
    __builtin_amdgcn_s_setprio(0);
  };

  // ---- 16 macro-steps, barrier-free ----
  #pragma unroll
  for (int T = 0; T < 16; ++T) {
    const int k = T >> 1, half = T & 1;
    if (half == 0) LI_LOAD(k);
    B_LOAD1(T);
    MMA0(half);
    if (T + 1 < 16) B_LOAD0(T + 1);
    MMA1(half);
  }

  // ---- epilogue: raw store + per-channel sums (no tail checks) ----
  float sm[2], sq[2];
  sm[0] = sm[1] = sq[0] = sq[1] = 0.f;
  #pragma unroll
  for (int mi = 0; mi < 2; ++mi) {
    #pragma unroll
    for (int rr = 0; rr < 4; ++rr) {
      long m = base_m + (mi << 4) + (quad << 2) + rr;
      #pragma unroll
      for (int ni = 0; ni < 2; ++ni) {
        float v = acc[mi][ni][rr];
        int n = (wave << 5) + (ni << 4) + row16;
        if (rawout) rawout[m * COUT + n] = (unsigned short)f2bf_u(v);
        else        out32[m * COUT + n] = v;
        sm[ni] += v;
        sq[ni] += v * v;
      }
    }
  }
  #pragma unroll
  for (int ni = 0; ni < 2; ++ni) {
    sm[ni] += __shfl_xor(sm[ni], 16);
    sm[ni] += __shfl_xor(sm[ni], 32);
    sq[ni] += __shfl_xor(sq[ni], 16);
    sq[ni] += __shfl_xor(sq[ni], 32);
  }
  if (quad == 0) {
    float* pb = partial + (long)blockIdx.x * 512;
    #pragma unroll
    for (int ni = 0; ni < 2; ++ni) {
      int n = (wave << 5) + (ni << 4) + row16;
      pb[n] = sm[ni];
      pb[n + 256] = sq[ni];
    }
  }
}

// ---------------------------------------------------------------------------
// Kernel 2: reduce partial[3125][512] -> partial2[64][512]
// ---------------------------------------------------------------------------
__global__ void reduce_kernel(const float* __restrict__ partial,
                              float* __restrict__ partial2) {
  const int j = blockIdx.x;       // 0..63
  const int c = threadIdx.x;      // 0..511
  const int b0 = j * 49;
  const int b1 = (b0 + 49 < NBLK) ? b0 + 49 : NBLK;
  float s = 0.f;
  for (int b = b0; b < b1; ++b) s += partial[(long)b * 512 + c];
  partial2[(long)j * 512 + c] = s;
}

// ---------------------------------------------------------------------------
// Kernel 3: partial2 -> scale/shift
// ---------------------------------------------------------------------------
__global__ void finalize_kernel(const float* __restrict__ partial2,
                                const float* __restrict__ gamma,
                                const float* __restrict__ beta,
                                float* __restrict__ ss) {
  int n = threadIdx.x;            // 0..255
  float s = 0.f, q = 0.f;
  #pragma unroll
  for (int j = 0; j < 64; ++j) {
    s += partial2[j * 512 + n];
    q += partial2[j * 512 + 256 + n];
  }
  const float inv = 1.0f / (float)MOUT;
  float mu = s * inv;
  float var = q * inv - mu * mu;
  float sc = rsqrtf(var + EPSV) * gamma[n];
  ss[n] = sc;
  ss[n + 256] = beta[n] - mu * sc;
}

// ---------------------------------------------------------------------------
// Kernel 4a: BN + ReLU from bf16 raw -> f32 out
// ---------------------------------------------------------------------------
__global__ void apply_bf16(const unsigned short* __restrict__ raw,
                           float* __restrict__ out,
                           const float* __restrict__ ss) {
  const int c0 = (threadIdx.x & 31) << 3;
  float scr[8], shr[8];
  #pragma unroll
  for (int j = 0; j < 8; ++j) { scr[j] = ss[c0 + j]; shr[j] = ss[c0 + j + 256]; }
  const long total = (long)MOUT * COUT / 8;
  const uint4* r4 = (const uint4*)raw;
  float4* o4 = (float4*)out;
  union { unsigned u; float f; } t;
  for (long i = (long)blockIdx.x * blockDim.x + threadIdx.x; i < total;
       i += (long)gridDim.x * blockDim.x) {
    uint4 v = r4[i];
    float4 a, b;
    t.u = v.x << 16;        a.x = t.f;
    t.u = v.x & 0xffff0000; a.y = t.f;
    t.u = v.y << 16;        a.z = t.f;
    t.u = v.y & 0xffff0000; a.w = t.f;
    t.u = v.z << 16;        b.x = t.f;
    t.u = v.z & 0xffff0000; b.y = t.f;
    t.u = v.w << 16;        b.z = t.f;
    t.u = v.w & 0xffff0000; b.w = t.f;
    a.x = fmaxf(fmaf(a.x, scr[0], shr[0]), 0.f);
    a.y = fmaxf(fmaf(a.y, scr[1], shr[1]), 0.f);
    a.z = fmaxf(fmaf(a.z, scr[2], shr[2]), 0.f);
    a.w = fmaxf(fmaf(a.w, scr[3], shr[3]), 0.f);
    b.x = fmaxf(fmaf(b.x, scr[4], shr[4]), 0.f);
    b.y = fmaxf(fmaf(b.y, scr[5], shr[5]), 0.f);
    b.z = fmaxf(fmaf(b.z, scr[6], shr[6]), 0.f);
    b.w = fmaxf(fmaf(b.w, scr[7], shr[7]), 0.f);
    o4[2 * i] = a;
    o4[2 * i + 1] = b;
  }
}

// ---------------------------------------------------------------------------
// Kernel 4b: in-place BN + ReLU on f32 out (fallback)
// ---------------------------------------------------------------------------
__global__ void apply_f32(float* __restrict__ out, const float* __restrict__ ss) {
  __shared__ float sc[256], sh[256];
  sc[threadIdx.x] = ss[threadIdx.x];
  sh[threadIdx.x] = ss[threadIdx.x + 256];
  __syncthreads();
  const long total = (long)MOUT * COUT / 4;
  float4* o4 = (float4*)out;
  for (long i = (long)blockIdx.x * blockDim.x + threadIdx.x; i < total;
       i += (long)gridDim.x * blockDim.x) {
    float4 v = o4[i];
    int c = (int)(i & 63) << 2;
    v.x = fmaxf(fmaf(v.x, sc[c],     sh[c]),     0.f);
    v.y = fmaxf(fmaf(v.y, sc[c + 1], sh[c + 1]), 0.f);
    v.z = fmaxf(fmaf(v.z, sc[c + 2], sh[c + 2]), 0.f);
    v.w = fmaxf(fmaf(v.w, sc[c + 3], sh[c + 3]), 0.f);
    o4[i] = v;
  }
}

// ---------------------------------------------------------------------------
extern "C" void kernel_launch(void* const* d_in, const int* in_sizes, int n_in,
                              void* d_out, int out_size, void* d_ws, size_t ws_size,
                              hipStream_t stream) {
  const float* feats = (const float*)d_in[0];
  const float* W     = (const float*)d_in[1];
  const float* gamma = (const float*)d_in[2];
  const float* beta  = (const float*)d_in[3];
  const int*   gidx  = (const int*)d_in[4];
  float* out = (float*)d_out;

  float* ss = (float*)d_ws;                                     // 2 KB
  unsigned short* Wt = (unsigned short*)((char*)d_ws + 4096);   // 512 KB
  float* partial  = (float*)((char*)d_ws + 4096 + 524288);      // 3125*512*4 = 6.4 MB
  float* partial2 = (float*)((char*)partial + (size_t)NBLK * 512 * 4);  // 128 KB
  size_t raw_off = 4096 + 524288 + (size_t)NBLK * 512 * 4 + 131072;
  raw_off = (raw_off + 255) & ~(size_t)255;
  const size_t RAW_BYTES = (size_t)MOUT * COUT * 2;
  bool bf16raw = ws_size >= raw_off + RAW_BYTES;
  unsigned short* raw = bf16raw ? (unsigned short*)((char*)d_ws + raw_off) : nullptr;

  hipLaunchKernelGGL(prep_kernel, dim3(16), dim3(256), 0, stream, W, Wt);
  hipLaunchKernelGGL(conv_kernel, dim3(NBLK), dim3(THREADS), 0, stream,
                     feats, Wt, gidx, raw, bf16raw ? nullptr : out, partial);
  hipLaunchKernelGGL(reduce_kernel, dim3(64), dim3(512), 0, stream,
                     partial, partial2);
  hipLaunchKernelGGL(finalize_kernel, dim3(1), dim3(256), 0, stream,
                     partial2, gamma, beta, ss);
  if (bf16raw)
    hipLaunchKernelGGL(apply_bf16, dim3(2048), dim3(256), 0, stream, raw, out, ss);
  else
    hipLaunchKernelGGL(apply_f32, dim3(2048), dim3(256), 0, stream, out, ss);
}

// Round 21
// 134.157 us; speedup vs baseline: 1.2420x; 1.2420x over previous
//
#include <hip/hip_runtime.h>
#include <hip/hip_bf16.h>
#include <stdint.h>

#define CIN 128
#define COUT 256
#define NIN 400000
#define MOUT 100000
#define KOFFS 8
#define EPSV 1e-4f
#define BM 64
#define NBLK ((MOUT + BM - 1) / BM)   // 1563
#define THREADS 512

typedef __attribute__((ext_vector_type(8))) short short8;
typedef __attribute__((ext_vector_type(4))) float f32x4;

__device__ __forceinline__ unsigned f2bf_u(float f) {
  union { float f; unsigned u; } v; v.f = f;
  return (v.u + 0x7FFFu + ((v.u >> 16) & 1u)) >> 16;  // RNE bf16
}

__device__ __forceinline__ unsigned pk2bf(float a, float b) {
  __hip_bfloat162 p = __float22bfloat162_rn(make_float2(a, b));
  union { __hip_bfloat162 h; unsigned u; } c; c.h = p;
  return c.u;                          // v_cvt_pk_bf16_f32, 1 instr
}

// ---------------------------------------------------------------------------
// Kernel 0: W[k][c][n] fp32 -> Wt in MFMA-fragment order (R14 layout).
// ---------------------------------------------------------------------------
__global__ void prep_kernel(const float* __restrict__ W,
                            unsigned short* __restrict__ Wt) {
  __shared__ unsigned short t[64][257];
  const int s = blockIdx.x;
  const int tid = threadIdx.x;  // 256
  const int koff = s >> 1;
  const int cbase = (s & 1) * 64;
  const float* Wk = W + koff * (CIN * COUT);
  #pragma unroll 8
  for (int c = 0; c < 64; ++c)
    t[c][tid] = (unsigned short)f2bf_u(Wk[(cbase + c) * COUT + tid]);
  __syncthreads();
  uint4* dst = (uint4*)((char*)Wt + s * 32768);
  #pragma unroll
  for (int p = 0; p < 8; ++p) {
    int f = p * 256 + tid;
    int wn = f >> 8, rem = f & 255;
    int g = rem >> 6, l = rem & 63;
    int ks = g >> 1, ni = g & 1;
    int n = wn * 32 + ni * 16 + (l & 15);
    int cb = ks * 32 + ((l >> 4) << 3);
    uint4 w;
    w.x = (unsigned)t[cb + 0][n] | ((unsigned)t[cb + 1][n] << 16);
    w.y = (unsigned)t[cb + 2][n] | ((unsigned)t[cb + 3][n] << 16);
    w.z = (unsigned)t[cb + 4][n] | ((unsigned)t[cb + 5][n] << 16);
    w.w = (unsigned)t[cb + 6][n] | ((unsigned)t[cb + 7][n] << 16);
    dst[f] = w;
  }
}

// ---------------------------------------------------------------------------
// Kernel 1: gather-GEMM conv — R18 base, K-loop software-pipelined with
// explicit X/Y register double-buffering (AF+B frags for sub-step h+1 loaded
// before MFMAs of h; cross-iteration liveness forces the compiler to
// allocate prefetch registers and break the LDS->MFMA serial chain).
// All 32 rulebook indices pre-loaded to registers (no LI in the loop).
// ---------------------------------------------------------------------------
__global__ __launch_bounds__(THREADS, 4) void conv_kernel(
    const float* __restrict__ feats,
    const unsigned short* __restrict__ Wt,
    const int* __restrict__ gidx,
    unsigned short* __restrict__ rawout,
    float* __restrict__ out32,
    float* __restrict__ partial) {
  __shared__ unsigned short Asm[257 * 128];   // 257 rows x 256 B (row 256 = 0)
  __shared__ int IDXs[BM * KOFFS];

  const int tid = threadIdx.x;
  const int lane = tid & 63;
  const int wave = tid >> 6;       // col-group 0..7 (32 cols each)
  const int row16 = lane & 15;
  const int quad = lane >> 4;
  const long base_m = (long)blockIdx.x * BM;
  const long in_base = 4 * base_m;
  const char* Wtc = (const char*)Wt;

  // ---- B frags for sub-step 0: issue FIRST (L2 latency under staging) ----
  short8 bX0, bX1, bY0, bY1;
  {
    const char* bp = Wtc + (wave << 12) + (lane << 4);
    bX0 = *(const short8*)bp;
    bX1 = *(const short8*)(bp + 1024);
  }

  for (int i = tid; i < BM * KOFFS; i += THREADS) {
    long m = base_m + (i >> 3);
    int idx = (m < MOUT) ? gidx[m * KOFFS + (i & 7)] : NIN;
    long li = (long)idx - in_base;
    IDXs[i] = ((unsigned long)li > 255ul) ? 256 : (int)li;
  }
  if (tid < 16) *(uint4*)((char*)Asm + 256 * 256 + tid * 16) = make_uint4(0, 0, 0, 0);

  // ---- linear A stage: 16 float4/thread, cvt_pk conversion ----
  {
    const float4* f4 = (const float4*)feats + in_base * 32;
    float4 v[16];
    if (in_base + 256 <= NIN) {
      #pragma unroll
      for (int p = 0; p < 16; ++p) v[p] = f4[p * THREADS + tid];
    } else {
      #pragma unroll
      for (int p = 0; p < 16; ++p) {
        int j = p * THREADS + tid;
        v[p] = (in_base + (j >> 5) < NIN) ? f4[j]
                                          : make_float4(0.f, 0.f, 0.f, 0.f);
      }
    }
    #pragma unroll
    for (int p = 0; p < 16; ++p) {
      int j = p * THREADS + tid;
      int row = j >> 5, ch4 = j & 31;
      uint2 w;
      w.x = pk2bf(v[p].x, v[p].y);
      w.y = pk2bf(v[p].z, v[p].w);
      *(uint2*)((char*)Asm + row * 256 + ((ch4 * 8) ^ ((row & 15) << 4))) = w;
    }
  }
  __syncthreads();

  // ---- all 32 rulebook indices -> registers (no LDS reads in loop) ----
  int lir0[8], lir1[8], lir2[8], lir3[8];
  #pragma unroll
  for (int k = 0; k < 8; ++k) {
    lir0[k] = IDXs[(row16) * 8 + k];
    lir1[k] = IDXs[(row16 + 16) * 8 + k];
    lir2[k] = IDXs[(row16 + 32) * 8 + k];
    lir3[k] = IDXs[(row16 + 48) * 8 + k];
  }

  auto AF = [&](int li, int inner) -> short8 {
    return *(const short8*)((const char*)Asm + li * 256 +
                            (inner ^ ((li & 15) << 4)));
  };

  f32x4 acc[4][2];
  #pragma unroll
  for (int mi = 0; mi < 4; ++mi)
    #pragma unroll
    for (int ni = 0; ni < 2; ++ni)
      acc[mi][ni] = (f32x4){0.f, 0.f, 0.f, 0.f};

  short8 aX0, aX1, aX2, aX3, aY0, aY1, aY2, aY3;

// sub-step h = 0..31: T = h>>1, ks = h&1, koff = h>>2, half = (h>>1)&1
#define AFLD(h, d0, d1, d2, d3) {                                         \
    const int inner_ = ((((h) >> 1) & 1) << 7) + (((h) & 1) << 6) + (quad << 4); \
    const int ko_ = (h) >> 2;                                             \
    d0 = AF(lir0[ko_], inner_); d1 = AF(lir1[ko_], inner_);               \
    d2 = AF(lir2[ko_], inner_); d3 = AF(lir3[ko_], inner_); }

#define BLD(h, e0, e1) {                                                  \
    const char* bp_ = Wtc + ((h) >> 1) * 32768 + (wave << 12) +           \
                      (((h) & 1) << 11) + (lane << 4);                    \
    e0 = *(const short8*)bp_; e1 = *(const short8*)(bp_ + 1024); }

#define MFMA8(a0, a1, a2, a3, b0, b1)                                     \
    __builtin_amdgcn_s_setprio(1);                                        \
    acc[0][0] = __builtin_amdgcn_mfma_f32_16x16x32_bf16(a0, b0, acc[0][0], 0, 0, 0); \
    acc[0][1] = __builtin_amdgcn_mfma_f32_16x16x32_bf16(a0, b1, acc[0][1], 0, 0, 0); \
    acc[1][0] = __builtin_amdgcn_mfma_f32_16x16x32_bf16(a1, b0, acc[1][0], 0, 0, 0); \
    acc[1][1] = __builtin_amdgcn_mfma_f32_16x16x32_bf16(a1, b1, acc[1][1], 0, 0, 0); \
    acc[2][0] = __builtin_amdgcn_mfma_f32_16x16x32_bf16(a2, b0, acc[2][0], 0, 0, 0); \
    acc[2][1] = __builtin_amdgcn_mfma_f32_16x16x32_bf16(a2, b1, acc[2][1], 0, 0, 0); \
    acc[3][0] = __builtin_amdgcn_mfma_f32_16x16x32_bf16(a3, b0, acc[3][0], 0, 0, 0); \
    acc[3][1] = __builtin_amdgcn_mfma_f32_16x16x32_bf16(a3, b1, acc[3][1], 0, 0, 0); \
    __builtin_amdgcn_s_setprio(0);

  // ---- prologue: current = X for sub-step 0 (B already in flight) ----
  AFLD(0, aX0, aX1, aX2, aX3);

  // ---- 32 sub-steps, X/Y ping-pong, prefetch h+1 before MFMA(h) ----
  #pragma unroll
  for (int hh = 0; hh < 32; hh += 2) {
    AFLD(hh + 1, aY0, aY1, aY2, aY3);      // prefetch next (LDS)
    BLD(hh + 1, bY0, bY1);                 // prefetch next (L2)
    MFMA8(aX0, aX1, aX2, aX3, bX0, bX1);   // compute current
    if (hh + 2 < 32) {
      AFLD(hh + 2, aX0, aX1, aX2, aX3);
      BLD(hh + 2, bX0, bX1);
    }
    MFMA8(aY0, aY1, aY2, aY3, bY0, bY1);
  }

#undef AFLD
#undef BLD
#undef MFMA8

  // ---- epilogue: raw store + per-channel sums (plain stores) ----
  float sm[2], sq[2];
  sm[0] = sm[1] = sq[0] = sq[1] = 0.f;
  #pragma unroll
  for (int mi = 0; mi < 4; ++mi) {
    #pragma unroll
    for (int rr = 0; rr < 4; ++rr) {
      long m = base_m + (mi << 4) + (quad << 2) + rr;
      bool ok = (m < MOUT);
      #pragma unroll
      for (int ni = 0; ni < 2; ++ni) {
        float v = acc[mi][ni][rr];
        int n = (wave << 5) + (ni << 4) + row16;
        if (ok) {
          if (rawout) rawout[m * COUT + n] = (unsigned short)f2bf_u(v);
          else        out32[m * COUT + n] = v;
        }
        sm[ni] += v;
        sq[ni] += v * v;
      }
    }
  }
  #pragma unroll
  for (int ni = 0; ni < 2; ++ni) {
    sm[ni] += __shfl_xor(sm[ni], 16);
    sm[ni] += __shfl_xor(sm[ni], 32);
    sq[ni] += __shfl_xor(sq[ni], 16);
    sq[ni] += __shfl_xor(sq[ni], 32);
  }
  if (quad == 0) {
    float* pb = partial + (long)blockIdx.x * 512;
    #pragma unroll
    for (int ni = 0; ni < 2; ++ni) {
      int n = (wave << 5) + (ni << 4) + row16;
      pb[n] = sm[ni];
      pb[n + 256] = sq[ni];
    }
  }
}

// ---------------------------------------------------------------------------
// Kernel 2: reduce partial[1563][512] -> partial2[64][512]
// ---------------------------------------------------------------------------
__global__ void reduce_kernel(const float* __restrict__ partial,
                              float* __restrict__ partial2) {
  const int j = blockIdx.x;       // 0..63
  const int c = threadIdx.x;      // 0..511
  const int b0 = j * 25;
  const int b1 = (b0 + 25 < NBLK) ? b0 + 25 : NBLK;
  float s = 0.f;
  for (int b = b0; b < b1; ++b) s += partial[(long)b * 512 + c];
  partial2[(long)j * 512 + c] = s;
}

// ---------------------------------------------------------------------------
// Kernel 3: partial2 -> scale/shift
// ---------------------------------------------------------------------------
__global__ void finalize_kernel(const float* __restrict__ partial2,
                                const float* __restrict__ gamma,
                                const float* __restrict__ beta,
                                float* __restrict__ ss) {
  int n = threadIdx.x;            // 0..255
  float s = 0.f, q = 0.f;
  #pragma unroll
  for (int j = 0; j < 64; ++j) {
    s += partial2[j * 512 + n];
    q += partial2[j * 512 + 256 + n];
  }
  const float inv = 1.0f / (float)MOUT;
  float mu = s * inv;
  float var = q * inv - mu * mu;
  float sc = rsqrtf(var + EPSV) * gamma[n];
  ss[n] = sc;
  ss[n + 256] = beta[n] - mu * sc;
}

// ---------------------------------------------------------------------------
// Kernel 4a: BN + ReLU from bf16 raw -> f32 out
// ---------------------------------------------------------------------------
__global__ void apply_bf16(const unsigned short* __restrict__ raw,
                           float* __restrict__ out,
                           const float* __restrict__ ss) {
  const int c0 = (threadIdx.x & 31) << 3;
  float scr[8], shr[8];
  #pragma unroll
  for (int j = 0; j < 8; ++j) { scr[j] = ss[c0 + j]; shr[j] = ss[c0 + j + 256]; }
  const long total = (long)MOUT * COUT / 8;
  const uint4* r4 = (const uint4*)raw;
  float4* o4 = (float4*)out;
  union { unsigned u; float f; } t;
  for (long i = (long)blockIdx.x * blockDim.x + threadIdx.x; i < total;
       i += (long)gridDim.x * blockDim.x) {
    uint4 v = r4[i];
    float4 a, b;
    t.u = v.x << 16;        a.x = t.f;
    t.u = v.x & 0xffff0000; a.y = t.f;
    t.u = v.y << 16;        a.z = t.f;
    t.u = v.y & 0xffff0000; a.w = t.f;
    t.u = v.z << 16;        b.x = t.f;
    t.u = v.z & 0xffff0000; b.y = t.f;
    t.u = v.w << 16;        b.z = t.f;
    t.u = v.w & 0xffff0000; b.w = t.f;
    a.x = fmaxf(fmaf(a.x, scr[0], shr[0]), 0.f);
    a.y = fmaxf(fmaf(a.y, scr[1], shr[1]), 0.f);
    a.z = fmaxf(fmaf(a.z, scr[2], shr[2]), 0.f);
    a.w = fmaxf(fmaf(a.w, scr[3], shr[3]), 0.f);
    b.x = fmaxf(fmaf(b.x, scr[4], shr[4]), 0.f);
    b.y = fmaxf(fmaf(b.y, scr[5], shr[5]), 0.f);
    b.z = fmaxf(fmaf(b.z, scr[6], shr[6]), 0.f);
    b.w = fmaxf(fmaf(b.w, scr[7], shr[7]), 0.f);
    o4[2 * i] = a;
    o4[2 * i + 1] = b;
  }
}

// ---------------------------------------------------------------------------
// Kernel 4b: in-place BN + ReLU on f32 out (fallback)
// ---------------------------------------------------------------------------
__global__ void apply_f32(float* __restrict__ out, const float* __restrict__ ss) {
  __shared__ float sc[256], sh[256];
  sc[threadIdx.x] = ss[threadIdx.x];
  sh[threadIdx.x] = ss[threadIdx.x + 256];
  __syncthreads();
  const long total = (long)MOUT * COUT / 4;
  float4* o4 = (float4*)out;
  for (long i = (long)blockIdx.x * blockDim.x + threadIdx.x; i < total;
       i += (long)gridDim.x * blockDim.x) {
    float4 v = o4[i];
    int c = (int)(i & 63) << 2;
    v.x = fmaxf(fmaf(v.x, sc[c],     sh[c]),     0.f);
    v.y = fmaxf(fmaf(v.y, sc[c + 1], sh[c + 1]), 0.f);
    v.z = fmaxf(fmaf(v.z, sc[c + 2], sh[c + 2]), 0.f);
    v.w = fmaxf(fmaf(v.w, sc[c + 3], sh[c + 3]), 0.f);
    o4[i] = v;
  }
}

// ---------------------------------------------------------------------------
extern "C" void kernel_launch(void* const* d_in, const int* in_sizes, int n_in,
                              void* d_out, int out_size, void* d_ws, size_t ws_size,
                              hipStream_t stream) {
  const float* feats = (const float*)d_in[0];
  const float* W     = (const float*)d_in[1];
  const float* gamma = (const float*)d_in[2];
  const float* beta  = (const float*)d_in[3];
  const int*   gidx  = (const int*)d_in[4];
  float* out = (float*)d_out;

  float* ss = (float*)d_ws;                                     // 2 KB
  unsigned short* Wt = (unsigned short*)((char*)d_ws + 4096);   // 512 KB
  float* partial  = (float*)((char*)d_ws + 4096 + 524288);      // 3.2 MB
  float* partial2 = (float*)((char*)partial + (size_t)NBLK * 512 * 4);  // 128 KB
  size_t raw_off = 4096 + 524288 + (size_t)NBLK * 512 * 4 + 131072;
  raw_off = (raw_off + 255) & ~(size_t)255;
  const size_t RAW_BYTES = (size_t)MOUT * COUT * 2;
  bool bf16raw = ws_size >= raw_off + RAW_BYTES;
  unsigned short* raw = bf16raw ? (unsigned short*)((char*)d_ws + raw_off) : nullptr;

  hipLaunchKernelGGL(prep_kernel, dim3(16), dim3(256), 0, stream, W, Wt);
  hipLaunchKernelGGL(conv_kernel, dim3(NBLK), dim3(THREADS), 0, stream,
                     feats, Wt, gidx, raw, bf16raw ? nullptr : out, partial);
  hipLaunchKernelGGL(reduce_kernel, dim3(64), dim3(512), 0, stream,
                     partial, partial2);
  hipLaunchKernelGGL(finalize_kernel, dim3(1), dim3(256), 0, stream,
                     partial2, gamma, beta, ss);
  if (bf16raw)
    hipLaunchKernelGGL(apply_bf16, dim3(2048), dim3(256), 0, stream, raw, out, ss);
  else
    hipLaunchKernelGGL(apply_f32, dim3(2048), dim3(256), 0, stream, out, ss);
}